// Round 7
// baseline (286.018 us; speedup 1.0000x reference)
//
#include <hip/hip_runtime.h>

// Problem constants (match reference)
#define B_ 64
#define T_ 4096
#define C_ 8
#define K_ 150

constexpr int TPB    = 512;   // threads per block (R7: 8 waves, was 4)
constexpr int NWAVES = TPB / 64;             // 8
constexpr int TCHUNK = 256;   // timesteps per block
constexpr int TWAVE  = TCHUNK / NWAVES;      // 32 timesteps per wave
constexpr int NACC   = 27;    // 24 num (3k x 8c) + 3 den per lane
constexpr int RED_ST = 29;    // red64 stride: gcd(29,32)=1 -> conflict-free
constexpr int NBLK   = B_ * (T_ / TCHUNK);   // 1024 main blocks

#if __has_builtin(__builtin_amdgcn_exp2f)
#define EXP2F(x) __builtin_amdgcn_exp2f(x)
#else
#define EXP2F(x) __expf((x) * 0.6931471805599453f)
#endif

typedef float v2f __attribute__((ext_vector_type(2)));

// Packed dual-FMA: d = a*b + c on both halves of a VGPR pair (v_pk_fma_f32).
__device__ __forceinline__ v2f pk_fma(v2f a, v2f b, v2f c) {
    v2f d;
    asm("v_pk_fma_f32 %0, %1, %2, %3" : "=v"(d) : "v"(a), "v"(b), "v"(c));
    return d;
}

// One DPP reduce step: v += dpp_shifted(v). Pure VALU (no LDS pipe, no waitcnt).
template <int CTRL>
__device__ __forceinline__ float dpp_add(float v) {
    int sh = __builtin_amdgcn_update_dpp(0, __float_as_int(v), CTRL, 0xf, 0xf, true);
    return v + __int_as_float(sh);
}

// Full wave64 sum, result broadcast (uniform) to all lanes via readlane.
__device__ __forceinline__ float wave_sum64(float v) {
    v = dpp_add<0x111>(v);  // row_shr:1
    v = dpp_add<0x112>(v);  // row_shr:2
    v = dpp_add<0x114>(v);  // row_shr:4
    v = dpp_add<0x118>(v);  // row_shr:8
    v = dpp_add<0x142>(v);  // row_bcast:15
    v = dpp_add<0x143>(v);  // row_bcast:31  -> lane 63 holds total
    return __int_as_float(__builtin_amdgcn_readlane(__float_as_int(v), 63));
}

// ---- fallback (atomic) path helpers ----------------------------------------
__global__ void zero_accum(float* __restrict__ patch, float* __restrict__ den_g) {
    int i = blockIdx.x * blockDim.x + threadIdx.x;
    int n_patch = B_ * K_ * C_;           // 76800
    int n_total = n_patch + B_ * K_;      // +9600
    if (i < n_patch)      patch[i] = 0.0f;
    else if (i < n_total) den_g[i - n_patch] = 0.0f;
}

__global__ void finalize_patch(float* __restrict__ patch, const float* __restrict__ den_g) {
    int i = blockIdx.x * blockDim.x + threadIdx.x;
    if (i < B_ * K_ * C_) patch[i] = patch[i] / (den_g[i / C_] + 1e-8f);
}

// ---- main kernel ------------------------------------------------------------
// R7: occupancy via GRID-TIMES-WAVES, not residency caps. R6 counters showed:
// WRITE_SIZE ideal (161.6 MB, no amplification), FETCH 4.7 MB, VALUBusy 5.4%,
// occupancy ~1/4 of a saturated kernel, hbm 1.1-2.3 TB/s vs fill's 6.6.
// Diagnosis: write-stream backpressure with only 16 waves/CU (grid 1024 =
// 4 blocks/CU; R5's launch_bounds lever raised a cap that was never binding).
// Fix: TPB=512 -> 8 waves/block -> 32 waves/CU (hardware max) at same grid.
// Falsified: VALU issue (R3), store alignment (R4), NT stores (R2, CACHED only).
template <bool USE_WS>
__global__ __launch_bounds__(TPB, 8) void softkmeans_main(
        const float* __restrict__ x,        // [B,T,C]
        const float* __restrict__ cent,     // [K,C]
        float* __restrict__ assign_out,     // [B,T,K]
        float* __restrict__ num_g,          // atomic path: [B,K,C] (in d_out)
        float* __restrict__ den_g,          // atomic path: [B,K]   (in d_ws)
        float* __restrict__ ws) {           // ws path: [NBLK][NACC][64]
    __shared__ float4 xt[TCHUNK * 2];       // 8 KB: x tile, [t][c] as 2x float4
    __shared__ float  red64[64][RED_ST];    // 7.4 KB: serialized wave reduction

    const int bx    = blockIdx.x;
    const int b     = bx >> 4;             // 16 chunks per batch
    const int chunk = bx & 15;
    const int t0    = chunk * TCHUNK;
    const int tid   = threadIdx.x;
    const int wave  = tid >> 6;
    const int lane  = tid & 63;

    // Stage x tile: 2048 contiguous floats = 512 float4, one per thread.
    const float4* xsrc = (const float4*)(x + ((size_t)b * T_ + t0) * C_);
    xt[tid] = xsrc[tid];

    // Centroid fragments in registers: lane owns k in {lane, lane+64, lane+128}.
    // Fold 2*log2(e) into cen and log2(e) into csq so the logit is already in
    // exp2 domain: e = exp2(dot(cen2,x) - csq2), starting the FMA chain at -csq2.
    const float LOG2E = 1.4426950408889634f;
    v2f  cen2[3][4];
    float csq[3];
#pragma unroll
    for (int j = 0; j < 3; ++j) {
        int k = lane + 64 * j;
        if (k < K_) {
            float s = 0.0f;
#pragma unroll
            for (int c = 0; c < C_; ++c) {
                float v = cent[k * C_ + c];
                cen2[j][c / 2][c & 1] = 2.0f * LOG2E * v;
                s += v * v;
            }
            csq[j] = LOG2E * s;
        } else {
            // exp2(-1e30) = 0: dead lane contributes nothing
#pragma unroll
            for (int p = 0; p < 4; ++p) cen2[j][p] = v2f{0.0f, 0.0f};
            csq[j] = 1e30f;
        }
    }

    v2f  num2[3][4] = {};
    float den[3] = {0.0f, 0.0f, 0.0f};

    __syncthreads();

    const int tl0 = wave * TWAVE;
    const unsigned rowbase = ((unsigned)(b * T_) + (unsigned)(t0 + tl0)) * K_ + (unsigned)lane;

#pragma unroll 2
    for (int tt = 0; tt < TWAVE; ++tt) {
        const int tl = tl0 + tt;
        // Broadcast LDS reads (same address across wave -> conflict-free).
        float4 x0 = xt[tl * 2];
        float4 x1 = xt[tl * 2 + 1];
        v2f xv2[4] = {v2f{x0.x, x0.y}, v2f{x0.z, x0.w},
                      v2f{x1.x, x1.y}, v2f{x1.z, x1.w}};

        // logit2_k = (2*x.c_k - |c_k|^2) * log2e  (|x|^2 cancels in softmax).
        float e[3];
#pragma unroll
        for (int j = 0; j < 3; ++j) {
            v2f d2 = pk_fma(cen2[j][0], xv2[0], v2f{-csq[j], 0.0f});
            d2 = pk_fma(cen2[j][1], xv2[1], d2);
            d2 = pk_fma(cen2[j][2], xv2[2], d2);
            d2 = pk_fma(cen2[j][3], xv2[3], d2);
            e[j] = EXP2F(d2.x + d2.y);
        }

        // Wave-wide sum over K via DPP (VALU-only). Dead lanes hold 0.
        float s = wave_sum64(e[0] + e[1] + e[2]);
        float inv = __builtin_amdgcn_rcpf(s);   // rel err ~1e-7, fine vs 2.4e-3 tol

        float a0 = e[0] * inv, a1 = e[1] * inv, a2 = e[2] * inv;

        // Plain cached stores (R2 lesson: L2 merges the contiguous 600B rows;
        // R4 showed alignment/instruction count is NOT the bottleneck).
        unsigned base = rowbase + (unsigned)(tt * K_);
        assign_out[base]      = a0;
        assign_out[base + 64] = a1;
        if (lane < K_ - 128) assign_out[base + 128] = a2;

        den[0] += a0; den[1] += a1; den[2] += a2;
        v2f a02 = v2f{a0, a0}, a12 = v2f{a1, a1}, a22 = v2f{a2, a2};
#pragma unroll
        for (int p = 0; p < 4; ++p) {
            num2[0][p] = pk_fma(a02, xv2[p], num2[0][p]);
            num2[1][p] = pk_fma(a12, xv2[p], num2[1][p]);
            num2[2][p] = pk_fma(a22, xv2[p], num2[2][p]);
        }
    }

    // Cross-wave reduction, serialized into red64[64][29] (7.4 KB):
    // wave 0 writes, waves 1..6 add in turn, wave 7 adds in-register and emits.
    // All __syncthreads() are reached by ALL waves (branches select work,
    // not barrier participation). Epilogue-only cost (~7 barriers).
    float mine[NACC];
#pragma unroll
    for (int j = 0; j < 3; ++j) {
#pragma unroll
        for (int p = 0; p < 4; ++p) {
            mine[j * C_ + 2 * p]     = num2[j][p].x;
            mine[j * C_ + 2 * p + 1] = num2[j][p].y;
        }
        mine[24 + j] = den[j];
    }

    if (wave == 0) {
#pragma unroll
        for (int i = 0; i < NACC; ++i) red64[lane][i] = mine[i];
    }
    __syncthreads();
#pragma unroll
    for (int w = 1; w < NWAVES - 1; ++w) {
        if (wave == w) {
#pragma unroll
            for (int i = 0; i < NACC; ++i) red64[lane][i] += mine[i];
        }
        __syncthreads();
    }

    if (wave == NWAVES - 1) {
        float acc[NACC];
#pragma unroll
        for (int i = 0; i < NACC; ++i) acc[i] = red64[lane][i] + mine[i];

        if constexpr (USE_WS) {
            // Per-block partial tile, coalesced: ws[bx][i][lane].
            // Dead lanes (k>=150) hold exact zeros; stored anyway for coalescing.
            float* dst = ws + (size_t)bx * (NACC * 64) + lane;
#pragma unroll
            for (int i = 0; i < NACC; ++i) dst[i * 64] = acc[i];
        } else {
#pragma unroll
            for (int j = 0; j < 3; ++j) {
                int k = lane + 64 * j;
                if (k < K_) {
#pragma unroll
                    for (int c = 0; c < C_; ++c)
                        atomicAdd(&num_g[((size_t)b * K_ + k) * C_ + c], acc[j * C_ + c]);
                    atomicAdd(&den_g[b * K_ + k], acc[24 + j]);
                }
            }
        }
    }
}

// Reduce the 16 chunk-partials per (b,k,c) and divide by den.
// Grid: B_*3 blocks (one per (b,j)), 512 threads: c = tid>>6 in [0,8), lane = k-64j.
__global__ __launch_bounds__(512) void finalize_ws(
        const float* __restrict__ ws,       // [NBLK][NACC][64]
        float* __restrict__ patch) {        // [B,K,C]
    __shared__ float dsh[64];
    const int b    = blockIdx.x / 3;
    const int j    = blockIdx.x % 3;
    const int c    = threadIdx.x >> 6;
    const int lane = threadIdx.x & 63;
    const int k    = lane + 64 * j;

    // num partial sum over 16 chunks (reads coalesced: lane is fastest dim).
    const float* src = ws + (size_t)(b * 16) * (NACC * 64) + lane;
    float s = 0.0f;
#pragma unroll
    for (int ch = 0; ch < 16; ++ch)
        s += src[ch * (NACC * 64) + (j * C_ + c) * 64];

    // den partial sum, computed once by wave 0 (c==0), shared via LDS.
    if (c == 0) {
        float d = 0.0f;
#pragma unroll
        for (int ch = 0; ch < 16; ++ch)
            d += src[ch * (NACC * 64) + (24 + j) * 64];
        dsh[lane] = d;
    }
    __syncthreads();

    if (k < K_)
        patch[((size_t)b * K_ + k) * C_ + c] = s / (dsh[lane] + 1e-8f);
}

extern "C" void kernel_launch(void* const* d_in, const int* in_sizes, int n_in,
                              void* d_out, int out_size, void* d_ws, size_t ws_size,
                              hipStream_t stream) {
    const float* x    = (const float*)d_in[0];   // [B,T,C]
    const float* cent = (const float*)d_in[1];   // [K,C]

    float* out        = (float*)d_out;
    float* patch      = out;                           // [B,K,C] = 76800 floats
    float* assign_out = out + (size_t)B_ * K_ * C_;    // [B,T,K]

    const size_t ws_need = (size_t)NBLK * NACC * 64 * sizeof(float);  // 7.08 MB

    if (ws_size >= ws_need) {
        // No-atomic path: per-block partials in d_ws, then one reduce kernel.
        float* ws = (float*)d_ws;
        softkmeans_main<true><<<NBLK, TPB, 0, stream>>>(
            x, cent, assign_out, nullptr, nullptr, ws);
        finalize_ws<<<B_ * 3, 512, 0, stream>>>(ws, patch);
    } else {
        // Fallback: verified atomic path (zero -> main(atomic) -> finalize).
        float* den_g = (float*)d_ws;                   // [B,K] = 38.4 KB
        int nz = B_ * K_ * C_ + B_ * K_;
        zero_accum<<<(nz + TPB - 1) / TPB, TPB, 0, stream>>>(patch, den_g);
        softkmeans_main<false><<<NBLK, TPB, 0, stream>>>(
            x, cent, assign_out, patch, den_g, nullptr);
        int np = B_ * K_ * C_;
        finalize_patch<<<(np + TPB - 1) / TPB, TPB, 0, stream>>>(patch, den_g);
    }
}

// Round 8
// 232.902 us; speedup vs baseline: 1.2281x; 1.2281x over previous
//
#include <hip/hip_runtime.h>

// Problem constants (match reference)
#define B_ 64
#define T_ 4096
#define C_ 8
#define K_ 150

constexpr int TPB    = 256;   // threads per block (R7 lesson: 16 waves/CU is the
                              // sweet spot; 32 waves/CU -> L2 write-RMW storm,
                              // FETCH 272MB, main 161us)
constexpr int TCHUNK = 256;   // timesteps per block
constexpr int TWAVE  = 64;    // timesteps per wave
constexpr int NACC   = 27;    // 24 num (3k x 8c) + 3 den per lane
constexpr int RED_ST = 29;    // red64 stride: gcd(29,32)=1 -> conflict-free
constexpr int NBLK   = B_ * (T_ / TCHUNK);   // 1024 main blocks
constexpr int WSSTR  = NACC * 64;            // 1728 floats per block partial

#if __has_builtin(__builtin_amdgcn_exp2f)
#define EXP2F(x) __builtin_amdgcn_exp2f(x)
#else
#define EXP2F(x) __expf((x) * 0.6931471805599453f)
#endif

typedef float v2f __attribute__((ext_vector_type(2)));

// Packed dual-FMA: d = a*b + c on both halves of a VGPR pair (v_pk_fma_f32).
__device__ __forceinline__ v2f pk_fma(v2f a, v2f b, v2f c) {
    v2f d;
    asm("v_pk_fma_f32 %0, %1, %2, %3" : "=v"(d) : "v"(a), "v"(b), "v"(c));
    return d;
}

// One DPP reduce step: v += dpp_shifted(v). Pure VALU (no LDS pipe, no waitcnt).
template <int CTRL>
__device__ __forceinline__ float dpp_add(float v) {
    int sh = __builtin_amdgcn_update_dpp(0, __float_as_int(v), CTRL, 0xf, 0xf, true);
    return v + __int_as_float(sh);
}

// Full wave64 sum, result broadcast (uniform) to all lanes via readlane.
__device__ __forceinline__ float wave_sum64(float v) {
    v = dpp_add<0x111>(v);  // row_shr:1
    v = dpp_add<0x112>(v);  // row_shr:2
    v = dpp_add<0x114>(v);  // row_shr:4
    v = dpp_add<0x118>(v);  // row_shr:8
    v = dpp_add<0x142>(v);  // row_bcast:15
    v = dpp_add<0x143>(v);  // row_bcast:31  -> lane 63 holds total
    return __int_as_float(__builtin_amdgcn_readlane(__float_as_int(v), 63));
}

// ---- fallback (atomic) path helpers ----------------------------------------
__global__ void zero_accum(float* __restrict__ patch, float* __restrict__ den_g) {
    int i = blockIdx.x * blockDim.x + threadIdx.x;
    int n_patch = B_ * K_ * C_;           // 76800
    int n_total = n_patch + B_ * K_;      // +9600
    if (i < n_patch)      patch[i] = 0.0f;
    else if (i < n_total) den_g[i - n_patch] = 0.0f;
}

__global__ void finalize_patch(float* __restrict__ patch, const float* __restrict__ den_g) {
    int i = blockIdx.x * blockDim.x + threadIdx.x;
    if (i < B_ * K_ * C_) patch[i] = patch[i] / (den_g[i / C_] + 1e-8f);
}

// ---- main kernel ------------------------------------------------------------
// R8: R3 structure (TPB=256, 16 waves/CU — the proven clean-store regime) with
// the finalize kernel FUSED via a last-block-per-batch election:
//   every block: write ws partial -> __threadfence (device release; needed
//   across non-coherent XCD L2s) -> atomicExch flag.
//   chunk-15 block of each batch: spin (acquire) on sibling flags, then reduce
//   16 partials and write patch. Flags poisoned 0xAA != 1 -> reset each call.
// Deadlock-free: spinners (64) only wait on non-spinner blocks, which always
// retire and free their slots.
// Falsified for main: VALU issue (R3), store pattern (R4), NT stores (R2,
// CACHED only), occupancy up (R7: 32 waves/CU -> RMW storm).
template <bool USE_WS>
__global__ __launch_bounds__(TPB, 4) void softkmeans_main(
        const float* __restrict__ x,        // [B,T,C]
        const float* __restrict__ cent,     // [K,C]
        float* __restrict__ assign_out,     // [B,T,K]
        float* __restrict__ num_g,          // atomic path: [B,K,C] (in d_out)
        float* __restrict__ den_g,          // atomic path: [B,K]   (in d_ws)
        float* __restrict__ ws,             // ws path: [NBLK][27*64] partials
        int*   __restrict__ flags,          // ws path: [NBLK] done-flags
        float* __restrict__ patch) {        // ws path: [B,K,C] output
    __shared__ float4 xt[TCHUNK * 2];       // 8 KB: x tile, [t][c] as 2x float4
    __shared__ float  red64[64][RED_ST];    // 7.4 KB: serialized wave reduction
    __shared__ float  dsh[3][64];           // 0.75 KB: den for fused finalize

    const int bx    = blockIdx.x;
    const int b     = bx >> 4;             // 16 chunks per batch
    const int chunk = bx & 15;
    const int t0    = chunk * TCHUNK;
    const int tid   = threadIdx.x;
    const int wave  = tid >> 6;
    const int lane  = tid & 63;

    // Stage x tile: 2048 contiguous floats, fully coalesced float4 loads.
    const float4* xsrc = (const float4*)(x + ((size_t)b * T_ + t0) * C_);
    xt[tid]       = xsrc[tid];
    xt[tid + TPB] = xsrc[tid + TPB];

    // Centroid fragments in registers: lane owns k in {lane, lane+64, lane+128}.
    // Fold 2*log2(e) into cen and log2(e) into csq so the logit is already in
    // exp2 domain: e = exp2(dot(cen2,x) - csq2), starting the FMA chain at -csq2.
    const float LOG2E = 1.4426950408889634f;
    v2f  cen2[3][4];
    float csq[3];
#pragma unroll
    for (int j = 0; j < 3; ++j) {
        int k = lane + 64 * j;
        if (k < K_) {
            float s = 0.0f;
#pragma unroll
            for (int c = 0; c < C_; ++c) {
                float v = cent[k * C_ + c];
                cen2[j][c / 2][c & 1] = 2.0f * LOG2E * v;
                s += v * v;
            }
            csq[j] = LOG2E * s;
        } else {
            // exp2(-1e30) = 0: dead lane contributes nothing
#pragma unroll
            for (int p = 0; p < 4; ++p) cen2[j][p] = v2f{0.0f, 0.0f};
            csq[j] = 1e30f;
        }
    }

    v2f  num2[3][4] = {};
    float den[3] = {0.0f, 0.0f, 0.0f};

    __syncthreads();

    const int tl0 = wave * TWAVE;
    const unsigned rowbase = ((unsigned)(b * T_) + (unsigned)(t0 + tl0)) * K_ + (unsigned)lane;

#pragma unroll 2
    for (int tt = 0; tt < TWAVE; ++tt) {
        const int tl = tl0 + tt;
        // Broadcast LDS reads (same address across wave -> conflict-free).
        float4 x0 = xt[tl * 2];
        float4 x1 = xt[tl * 2 + 1];
        v2f xv2[4] = {v2f{x0.x, x0.y}, v2f{x0.z, x0.w},
                      v2f{x1.x, x1.y}, v2f{x1.z, x1.w}};

        // logit2_k = (2*x.c_k - |c_k|^2) * log2e  (|x|^2 cancels in softmax).
        float e[3];
#pragma unroll
        for (int j = 0; j < 3; ++j) {
            v2f d2 = pk_fma(cen2[j][0], xv2[0], v2f{-csq[j], 0.0f});
            d2 = pk_fma(cen2[j][1], xv2[1], d2);
            d2 = pk_fma(cen2[j][2], xv2[2], d2);
            d2 = pk_fma(cen2[j][3], xv2[3], d2);
            e[j] = EXP2F(d2.x + d2.y);
        }

        // Wave-wide sum over K via DPP (VALU-only). Dead lanes hold 0.
        float s = wave_sum64(e[0] + e[1] + e[2]);
        float inv = __builtin_amdgcn_rcpf(s);   // rel err ~1e-7, fine vs 2.4e-3 tol

        float a0 = e[0] * inv, a1 = e[1] * inv, a2 = e[2] * inv;

        // Plain cached stores (R2: L2 merges contiguous 600B rows; R4: pattern
        // is not the bottleneck at 16 waves/CU).
        unsigned base = rowbase + (unsigned)(tt * K_);
        assign_out[base]      = a0;
        assign_out[base + 64] = a1;
        if (lane < K_ - 128) assign_out[base + 128] = a2;

        den[0] += a0; den[1] += a1; den[2] += a2;
        v2f a02 = v2f{a0, a0}, a12 = v2f{a1, a1}, a22 = v2f{a2, a2};
#pragma unroll
        for (int p = 0; p < 4; ++p) {
            num2[0][p] = pk_fma(a02, xv2[p], num2[0][p]);
            num2[1][p] = pk_fma(a12, xv2[p], num2[1][p]);
            num2[2][p] = pk_fma(a22, xv2[p], num2[2][p]);
        }
    }

    // Cross-wave reduction, serialized into red64[64][29] (7.4 KB):
    // wave 0 writes, waves 1-2 add, wave 3 adds in-register and emits.
    // All __syncthreads() are reached by ALL waves.
    float mine[NACC];
#pragma unroll
    for (int j = 0; j < 3; ++j) {
#pragma unroll
        for (int p = 0; p < 4; ++p) {
            mine[j * C_ + 2 * p]     = num2[j][p].x;
            mine[j * C_ + 2 * p + 1] = num2[j][p].y;
        }
        mine[24 + j] = den[j];
    }

    if (wave == 0) {
#pragma unroll
        for (int i = 0; i < NACC; ++i) red64[lane][i] = mine[i];
    }
    __syncthreads();
    if (wave == 1) {
#pragma unroll
        for (int i = 0; i < NACC; ++i) red64[lane][i] += mine[i];
    }
    __syncthreads();
    if (wave == 2) {
#pragma unroll
        for (int i = 0; i < NACC; ++i) red64[lane][i] += mine[i];
    }
    __syncthreads();

    if (wave == 3) {
        float acc[NACC];
#pragma unroll
        for (int i = 0; i < NACC; ++i) acc[i] = red64[lane][i] + mine[i];

        if constexpr (USE_WS) {
            // Per-block partial tile, coalesced: ws[bx][i][lane].
            float* dst = ws + (size_t)bx * WSSTR + lane;
#pragma unroll
            for (int i = 0; i < NACC; ++i) dst[i * 64] = acc[i];
            // Release: make partial visible device-wide (cross-XCD), then flag.
            // vmcnt is per-wave, so this wave's fence covers all 64 lanes' stores.
            __threadfence();
            if (lane == 0) atomicExch(&flags[bx], 1);
        } else {
#pragma unroll
            for (int j = 0; j < 3; ++j) {
                int k = lane + 64 * j;
                if (k < K_) {
#pragma unroll
                    for (int c = 0; c < C_; ++c)
                        atomicAdd(&num_g[((size_t)b * K_ + k) * C_ + c], acc[j * C_ + c]);
                    atomicAdd(&den_g[b * K_ + k], acc[24 + j]);
                }
            }
        }
    }

    if constexpr (USE_WS) {
        // Fused finalize: chunk-15 block of each batch reduces the 16 partials.
        if (chunk == 15) {
            // Spin on sibling flags (threads 0..15 each poll one chunk; own
            // flag already set). Acquire pairs with writers' release fence.
            if (tid < 16) {
                const int* f = &flags[b * 16 + tid];
                while (__hip_atomic_load(f, __ATOMIC_ACQUIRE,
                                         __HIP_MEMORY_SCOPE_AGENT) != 1) {
                    __builtin_amdgcn_s_sleep(8);
                }
            }
            __syncthreads();

            const float* src = ws + (size_t)(b * 16) * WSSTR + lane;
            // den sums (wave 0): dsh[j][lane] = sum_ch partial_den.
            if (wave == 0) {
#pragma unroll
                for (int j = 0; j < 3; ++j) {
                    float d = 0.0f;
#pragma unroll
                    for (int ch = 0; ch < 16; ++ch)
                        d += src[ch * WSSTR + (24 + j) * 64];
                    dsh[j][lane] = d;
                }
            }
            __syncthreads();

            // num sums + divide: wave w handles c in {2w, 2w+1}; lane is the
            // k-part (coalesced: lane contiguous in ws).
#pragma unroll
            for (int j = 0; j < 3; ++j) {
                const int k = lane + 64 * j;
                if (k < K_) {
                    float invd = 1.0f / (dsh[j][lane] + 1e-8f);
#pragma unroll
                    for (int cc = 0; cc < 2; ++cc) {
                        const int c = 2 * wave + cc;
                        float s = 0.0f;
#pragma unroll
                        for (int ch = 0; ch < 16; ++ch)
                            s += src[ch * WSSTR + (j * C_ + c) * 64];
                        patch[((size_t)b * K_ + k) * C_ + c] = s * invd;
                    }
                }
            }
        }
    }
}

extern "C" void kernel_launch(void* const* d_in, const int* in_sizes, int n_in,
                              void* d_out, int out_size, void* d_ws, size_t ws_size,
                              hipStream_t stream) {
    const float* x    = (const float*)d_in[0];   // [B,T,C]
    const float* cent = (const float*)d_in[1];   // [K,C]

    float* out        = (float*)d_out;
    float* patch      = out;                           // [B,K,C] = 76800 floats
    float* assign_out = out + (size_t)B_ * K_ * C_;    // [B,T,K]

    const size_t ws_part  = (size_t)NBLK * WSSTR * sizeof(float);    // 7.08 MB
    const size_t ws_need  = ws_part + (size_t)NBLK * sizeof(int);    // +4 KB

    if (ws_size >= ws_need) {
        // Single fused kernel: partials + flag election + in-kernel finalize.
        float* ws    = (float*)d_ws;
        int*   flags = (int*)((char*)d_ws + ws_part);
        softkmeans_main<true><<<NBLK, TPB, 0, stream>>>(
            x, cent, assign_out, nullptr, nullptr, ws, flags, patch);
    } else {
        // Fallback: verified atomic path (zero -> main(atomic) -> finalize).
        float* den_g = (float*)d_ws;                   // [B,K] = 38.4 KB
        int nz = B_ * K_ * C_ + B_ * K_;
        zero_accum<<<(nz + TPB - 1) / TPB, TPB, 0, stream>>>(patch, den_g);
        softkmeans_main<false><<<NBLK, TPB, 0, stream>>>(
            x, cent, assign_out, patch, den_g, nullptr, nullptr, nullptr);
        int np = B_ * K_ * C_;
        finalize_patch<<<(np + TPB - 1) / TPB, TPB, 0, stream>>>(patch, den_g);
    }
}

// Round 9
// 171.727 us; speedup vs baseline: 1.6655x; 1.3562x over previous
//
#include <hip/hip_runtime.h>

// Problem constants (match reference)
#define B_ 64
#define T_ 4096
#define C_ 8
#define K_ 150

constexpr int TPB    = 256;   // 16 waves/CU: R7 proved 32 waves/CU => L2 RMW storm
constexpr int TCHUNK = 256;   // timesteps per block
constexpr int TWAVE  = 64;    // timesteps per wave
constexpr int NACC   = 27;    // 24 num (3k x 8c) + 3 den per lane
constexpr int RED_ST = 29;    // red64 stride: gcd(29,32)=1 -> conflict-free
constexpr int NBLK   = B_ * (T_ / TCHUNK);   // 1024 main blocks
constexpr int WSSTR  = NACC * 64;            // 1728 floats per block partial

#if __has_builtin(__builtin_amdgcn_exp2f)
#define EXP2F(x) __builtin_amdgcn_exp2f(x)
#else
#define EXP2F(x) __expf((x) * 0.6931471805599453f)
#endif

typedef float v2f __attribute__((ext_vector_type(2)));

// Packed dual-FMA: d = a*b + c on both halves of a VGPR pair (v_pk_fma_f32).
__device__ __forceinline__ v2f pk_fma(v2f a, v2f b, v2f c) {
    v2f d;
    asm("v_pk_fma_f32 %0, %1, %2, %3" : "=v"(d) : "v"(a), "v"(b), "v"(c));
    return d;
}

// One DPP reduce step: v += dpp_shifted(v). Pure VALU (no LDS pipe, no waitcnt).
template <int CTRL>
__device__ __forceinline__ float dpp_add(float v) {
    int sh = __builtin_amdgcn_update_dpp(0, __float_as_int(v), CTRL, 0xf, 0xf, true);
    return v + __int_as_float(sh);
}

// DUAL wave64 sum: two independent reductions interleaved instruction-by-
// instruction so the ~25-cyc DPP latencies of the two trees overlap (R9: the
// single-chain version left each wave with only one chain in flight ->
// ~2600 cy/iter stalls vs ~350 cy chain; see R8 post-mortem).
__device__ __forceinline__ void wave_sum64x2(float& a, float& b) {
    a = dpp_add<0x111>(a);  b = dpp_add<0x111>(b);   // row_shr:1
    a = dpp_add<0x112>(a);  b = dpp_add<0x112>(b);   // row_shr:2
    a = dpp_add<0x114>(a);  b = dpp_add<0x114>(b);   // row_shr:4
    a = dpp_add<0x118>(a);  b = dpp_add<0x118>(b);   // row_shr:8
    a = dpp_add<0x142>(a);  b = dpp_add<0x142>(b);   // row_bcast:15
    a = dpp_add<0x143>(a);  b = dpp_add<0x143>(b);   // row_bcast:31
    a = __int_as_float(__builtin_amdgcn_readlane(__float_as_int(a), 63));
    b = __int_as_float(__builtin_amdgcn_readlane(__float_as_int(b), 63));
}

// ---- fallback (atomic) path helpers ----------------------------------------
__global__ void zero_accum(float* __restrict__ patch, float* __restrict__ den_g) {
    int i = blockIdx.x * blockDim.x + threadIdx.x;
    int n_patch = B_ * K_ * C_;           // 76800
    int n_total = n_patch + B_ * K_;      // +9600
    if (i < n_patch)      patch[i] = 0.0f;
    else if (i < n_total) den_g[i - n_patch] = 0.0f;
}

__global__ void finalize_patch(float* __restrict__ patch, const float* __restrict__ den_g) {
    int i = blockIdx.x * blockDim.x + threadIdx.x;
    if (i < B_ * K_ * C_) patch[i] = patch[i] / (den_g[i / C_] + 1e-8f);
}

// ---- main kernel ------------------------------------------------------------
// R9: R1/R6 frame (TPB=256, 16 waves/CU, separate finalize, NO fence/fusion —
// R8 showed __threadfence's L2 writeback costs ~40us) + explicit 2-row ILP:
// each iteration computes rows tt and tt+1 with interleaved independent
// chains (dual DPP tree), x2 via #pragma unroll -> up to 4 chains in flight.
// Falsified: VALU issue (R3), store pattern (R4), NT stores (R2), fence (R8),
// occupancy up (R7: RMW storm), occupancy caps (R5/R6).
template <bool USE_WS>
__global__ __launch_bounds__(TPB, 4) void softkmeans_main(
        const float* __restrict__ x,        // [B,T,C]
        const float* __restrict__ cent,     // [K,C]
        float* __restrict__ assign_out,     // [B,T,K]
        float* __restrict__ num_g,          // atomic path: [B,K,C] (in d_out)
        float* __restrict__ den_g,          // atomic path: [B,K]   (in d_ws)
        float* __restrict__ ws) {           // ws path: [NBLK][NACC][64]
    __shared__ float4 xt[TCHUNK * 2];       // 8 KB: x tile, [t][c] as 2x float4
    __shared__ float  red64[64][RED_ST];    // 7.4 KB: serialized wave reduction

    const int bx    = blockIdx.x;
    const int b     = bx >> 4;             // 16 chunks per batch
    const int chunk = bx & 15;
    const int t0    = chunk * TCHUNK;
    const int tid   = threadIdx.x;
    const int wave  = tid >> 6;
    const int lane  = tid & 63;

    // Stage x tile: 2048 contiguous floats, fully coalesced float4 loads.
    const float4* xsrc = (const float4*)(x + ((size_t)b * T_ + t0) * C_);
    xt[tid]       = xsrc[tid];
    xt[tid + TPB] = xsrc[tid + TPB];

    // Centroid fragments in registers: lane owns k in {lane, lane+64, lane+128}.
    // Fold 2*log2(e) into cen and log2(e) into csq so the logit is already in
    // exp2 domain: e = exp2(dot(cen2,x) - csq2), starting the FMA chain at -csq2.
    const float LOG2E = 1.4426950408889634f;
    v2f  cen2[3][4];
    float csq[3];
#pragma unroll
    for (int j = 0; j < 3; ++j) {
        int k = lane + 64 * j;
        if (k < K_) {
            float s = 0.0f;
#pragma unroll
            for (int c = 0; c < C_; ++c) {
                float v = cent[k * C_ + c];
                cen2[j][c / 2][c & 1] = 2.0f * LOG2E * v;
                s += v * v;
            }
            csq[j] = LOG2E * s;
        } else {
            // exp2(-1e30) = 0: dead lane contributes nothing
#pragma unroll
            for (int p = 0; p < 4; ++p) cen2[j][p] = v2f{0.0f, 0.0f};
            csq[j] = 1e30f;
        }
    }

    v2f  num2[3][4] = {};
    float den[3] = {0.0f, 0.0f, 0.0f};

    __syncthreads();

    const int tl0 = wave * TWAVE;
    const unsigned rowbase = ((unsigned)(b * T_) + (unsigned)(t0 + tl0)) * K_ + (unsigned)lane;

#pragma unroll 2
    for (int tt = 0; tt < TWAVE; tt += 2) {
        const int tl = tl0 + tt;
        // Broadcast LDS reads for BOTH rows up front (issue together; single
        // lgkmcnt wait covers all four b128 reads).
        float4 xa0 = xt[tl * 2],     xa1 = xt[tl * 2 + 1];
        float4 xb0 = xt[tl * 2 + 2], xb1 = xt[tl * 2 + 3];
        v2f xa[4] = {v2f{xa0.x, xa0.y}, v2f{xa0.z, xa0.w},
                     v2f{xa1.x, xa1.y}, v2f{xa1.z, xa1.w}};
        v2f xb[4] = {v2f{xb0.x, xb0.y}, v2f{xb0.z, xb0.w},
                     v2f{xb1.x, xb1.y}, v2f{xb1.z, xb1.w}};

        // Two independent logit/exp chains (rows tt, tt+1), interleaved.
        float ea[3], eb[3];
#pragma unroll
        for (int j = 0; j < 3; ++j) {
            v2f da = pk_fma(cen2[j][0], xa[0], v2f{-csq[j], 0.0f});
            v2f db = pk_fma(cen2[j][0], xb[0], v2f{-csq[j], 0.0f});
            da = pk_fma(cen2[j][1], xa[1], da);
            db = pk_fma(cen2[j][1], xb[1], db);
            da = pk_fma(cen2[j][2], xa[2], da);
            db = pk_fma(cen2[j][2], xb[2], db);
            da = pk_fma(cen2[j][3], xa[3], da);
            db = pk_fma(cen2[j][3], xb[3], db);
            ea[j] = EXP2F(da.x + da.y);
            eb[j] = EXP2F(db.x + db.y);
        }

        // Dual wave-wide sums (interleaved DPP trees). Dead lanes hold 0.
        float sa = ea[0] + ea[1] + ea[2];
        float sb = eb[0] + eb[1] + eb[2];
        wave_sum64x2(sa, sb);
        float inva = __builtin_amdgcn_rcpf(sa);  // rel err ~1e-7 vs 2.4e-3 tol
        float invb = __builtin_amdgcn_rcpf(sb);

        float a0 = ea[0] * inva, a1 = ea[1] * inva, a2 = ea[2] * inva;
        float b0 = eb[0] * invb, b1 = eb[1] * invb, b2 = eb[2] * invb;

        // Plain cached stores (R2: L2 merges the contiguous 600B rows; R4:
        // alignment/count not the bottleneck; R8: never fence mid-stream).
        unsigned basea = rowbase + (unsigned)(tt * K_);
        unsigned baseb = basea + (unsigned)K_;
        assign_out[basea]      = a0;
        assign_out[baseb]      = b0;
        assign_out[basea + 64] = a1;
        assign_out[baseb + 64] = b1;
        if (lane < K_ - 128) {
            assign_out[basea + 128] = a2;
            assign_out[baseb + 128] = b2;
        }

        den[0] += a0 + b0; den[1] += a1 + b1; den[2] += a2 + b2;
        v2f a02 = v2f{a0, a0}, a12 = v2f{a1, a1}, a22 = v2f{a2, a2};
        v2f b02 = v2f{b0, b0}, b12 = v2f{b1, b1}, b22 = v2f{b2, b2};
#pragma unroll
        for (int p = 0; p < 4; ++p) {
            num2[0][p] = pk_fma(a02, xa[p], num2[0][p]);
            num2[1][p] = pk_fma(a12, xa[p], num2[1][p]);
            num2[2][p] = pk_fma(a22, xa[p], num2[2][p]);
            num2[0][p] = pk_fma(b02, xb[p], num2[0][p]);
            num2[1][p] = pk_fma(b12, xb[p], num2[1][p]);
            num2[2][p] = pk_fma(b22, xb[p], num2[2][p]);
        }
    }

    // Cross-wave reduction, serialized into red64[64][29] (7.4 KB):
    // wave 0 writes, waves 1-2 add, wave 3 adds in-register and emits.
    // All __syncthreads() reached by ALL waves.
    float mine[NACC];
#pragma unroll
    for (int j = 0; j < 3; ++j) {
#pragma unroll
        for (int p = 0; p < 4; ++p) {
            mine[j * C_ + 2 * p]     = num2[j][p].x;
            mine[j * C_ + 2 * p + 1] = num2[j][p].y;
        }
        mine[24 + j] = den[j];
    }

    if (wave == 0) {
#pragma unroll
        for (int i = 0; i < NACC; ++i) red64[lane][i] = mine[i];
    }
    __syncthreads();
    if (wave == 1) {
#pragma unroll
        for (int i = 0; i < NACC; ++i) red64[lane][i] += mine[i];
    }
    __syncthreads();
    if (wave == 2) {
#pragma unroll
        for (int i = 0; i < NACC; ++i) red64[lane][i] += mine[i];
    }
    __syncthreads();

    if (wave == 3) {
        float acc[NACC];
#pragma unroll
        for (int i = 0; i < NACC; ++i) acc[i] = red64[lane][i] + mine[i];

        if constexpr (USE_WS) {
            // Per-block partial tile, coalesced: ws[bx][i][lane]. No fence, no
            // flags — finalize_ws is a separate kernel (stream-ordered).
            float* dst = ws + (size_t)bx * WSSTR + lane;
#pragma unroll
            for (int i = 0; i < NACC; ++i) dst[i * 64] = acc[i];
        } else {
#pragma unroll
            for (int j = 0; j < 3; ++j) {
                int k = lane + 64 * j;
                if (k < K_) {
#pragma unroll
                    for (int c = 0; c < C_; ++c)
                        atomicAdd(&num_g[((size_t)b * K_ + k) * C_ + c], acc[j * C_ + c]);
                    atomicAdd(&den_g[b * K_ + k], acc[24 + j]);
                }
            }
        }
    }
}

// Reduce the 16 chunk-partials per (b,k,c) and divide by den.
// Grid: B_*3 blocks (one per (b,j)), 512 threads: c = tid>>6 in [0,8), lane = k-64j.
__global__ __launch_bounds__(512) void finalize_ws(
        const float* __restrict__ ws,       // [NBLK][NACC][64]
        float* __restrict__ patch) {        // [B,K,C]
    __shared__ float dsh[64];
    const int b    = blockIdx.x / 3;
    const int j    = blockIdx.x % 3;
    const int c    = threadIdx.x >> 6;
    const int lane = threadIdx.x & 63;
    const int k    = lane + 64 * j;

    // num partial sum over 16 chunks (reads coalesced: lane is fastest dim).
    const float* src = ws + (size_t)(b * 16) * WSSTR + lane;
    float s = 0.0f;
#pragma unroll
    for (int ch = 0; ch < 16; ++ch)
        s += src[ch * WSSTR + (j * C_ + c) * 64];

    // den partial sum, computed once by wave 0 (c==0), shared via LDS.
    if (c == 0) {
        float d = 0.0f;
#pragma unroll
        for (int ch = 0; ch < 16; ++ch)
            d += src[ch * WSSTR + (24 + j) * 64];
        dsh[lane] = d;
    }
    __syncthreads();

    if (k < K_)
        patch[((size_t)b * K_ + k) * C_ + c] = s / (dsh[lane] + 1e-8f);
}

extern "C" void kernel_launch(void* const* d_in, const int* in_sizes, int n_in,
                              void* d_out, int out_size, void* d_ws, size_t ws_size,
                              hipStream_t stream) {
    const float* x    = (const float*)d_in[0];   // [B,T,C]
    const float* cent = (const float*)d_in[1];   // [K,C]

    float* out        = (float*)d_out;
    float* patch      = out;                           // [B,K,C] = 76800 floats
    float* assign_out = out + (size_t)B_ * K_ * C_;    // [B,T,K]

    const size_t ws_need = (size_t)NBLK * WSSTR * sizeof(float);  // 7.08 MB

    if (ws_size >= ws_need) {
        // No-atomic path: per-block partials in d_ws, then one reduce kernel.
        float* ws = (float*)d_ws;
        softkmeans_main<true><<<NBLK, TPB, 0, stream>>>(
            x, cent, assign_out, nullptr, nullptr, ws);
        finalize_ws<<<B_ * 3, 512, 0, stream>>>(ws, patch);
    } else {
        // Fallback: verified atomic path (zero -> main(atomic) -> finalize).
        float* den_g = (float*)d_ws;                   // [B,K] = 38.4 KB
        int nz = B_ * K_ * C_ + B_ * K_;
        zero_accum<<<(nz + TPB - 1) / TPB, TPB, 0, stream>>>(patch, den_g);
        softkmeans_main<false><<<NBLK, TPB, 0, stream>>>(
            x, cent, assign_out, patch, den_g, nullptr);
        int np = B_ * K_ * C_;
        finalize_patch<<<(np + TPB - 1) / TPB, TPB, 0, stream>>>(patch, den_g);
    }
}